// Round 1
// baseline (4382.579 us; speedup 1.0000x reference)
//
#include <hip/hip_runtime.h>
#include <math.h>

#define DEV __device__ __forceinline__

DEV float gelu_exact(float x){ return 0.5f*x*(1.0f+erff(x*0.70710678118654752440f)); }

// ======================= Fourier-encode data grid =======================
// data: (8, 16384, 29). ch0..2 = 0, ch3..28 = enc(h,w) broadcast over batch.
__global__ __launch_bounds__(256) void k_encode(float* __restrict__ data)
{
  int p = blockIdx.x*256 + threadIdx.x;      // 0..16383 exactly
  int hh = p >> 7, ww = p & 127;
  float y = -1.0f + hh*(2.0f/127.0f);
  float x = -1.0f + ww*(2.0f/127.0f);
  float e[26];
  #pragma unroll
  for (int i=0;i<6;i++){
    // scales = 2 ** linspace(1, log2(5), 6); step = (log2(5)-1)/5
    float sc = exp2f(1.0f + i*0.26438561897747245f) * 3.14159265358979323846f;
    e[i]     = sinf(y*sc);
    e[6+i]   = cosf(y*sc);
    e[13+i]  = sinf(x*sc);
    e[19+i]  = cosf(x*sc);
  }
  e[12]=y; e[25]=x;
  #pragma unroll
  for (int b=0;b<8;b++){
    float* dr = data + ((size_t)(b*16384 + p))*29;
    dr[0]=0.f; dr[1]=0.f; dr[2]=0.f;
    #pragma unroll
    for (int c=0;c<26;c++) dr[3+c]=e[c];
  }
}

// ======================= lat = x @ W_l2l + b + latents =======================
// x (8,512), W (512,131072), out lat (8,256,512) flat = (8,131072)
__global__ __launch_bounds__(256) void k_l2l(const float* __restrict__ x,
    const float* __restrict__ Wl, const float* __restrict__ bl,
    const float* __restrict__ latents, float* __restrict__ lat)
{
  __shared__ float xs[8*512];
  int tid = threadIdx.x;
  for (int idx=tid; idx<4096; idx+=256) xs[idx]=x[idx];
  __syncthreads();
  int nIdx = blockIdx.x*256 + tid;           // 0..131071
  float acc[8] = {0,0,0,0,0,0,0,0};
  for (int k=0;k<512;k++){
    float w = Wl[(size_t)k*131072 + nIdx];
    #pragma unroll
    for (int m=0;m<8;m++) acc[m] += xs[m*512+k]*w;
  }
  float add = bl[nIdx] + latents[nIdx];
  #pragma unroll
  for (int m=0;m<8;m++) lat[(size_t)m*131072 + nIdx] = acc[m] + add;
}

// ======================= LayerNorm, D=512, one block per row =======================
__global__ __launch_bounds__(256) void k_ln512(const float* __restrict__ X,
    const float* __restrict__ g, const float* __restrict__ bv, float* __restrict__ Y)
{
  __shared__ float red[8];
  int row = blockIdx.x, tid = threadIdx.x;
  const float* x = X + (size_t)row*512;
  float v0 = x[tid], v1 = x[tid+256];
  float s = v0+v1;
  #pragma unroll
  for (int off=32; off; off>>=1) s += __shfl_xor(s, off);
  if ((tid&63)==0) red[tid>>6] = s;
  __syncthreads();
  float mean = (red[0]+red[1]+red[2]+red[3]) * (1.0f/512.0f);
  float d0 = v0-mean, d1 = v1-mean;
  float q = d0*d0 + d1*d1;
  #pragma unroll
  for (int off=32; off; off>>=1) q += __shfl_xor(q, off);
  if ((tid&63)==0) red[4+(tid>>6)] = q;
  __syncthreads();
  float var = (red[4]+red[5]+red[6]+red[7]) * (1.0f/512.0f);
  float rstd = rsqrtf(var + 1e-5f);
  Y[(size_t)row*512 + tid]     = d0*rstd*g[tid]     + bv[tid];
  Y[(size_t)row*512 + tid+256] = d1*rstd*g[tid+256] + bv[tid+256];
}

// ======================= LayerNorm, D=29, one thread per row =======================
__global__ __launch_bounds__(256) void k_ln29(const float* __restrict__ X,
    const float* __restrict__ g, const float* __restrict__ bv, float* __restrict__ Y)
{
  int r = blockIdx.x*256 + threadIdx.x;      // rows = 131072 exactly
  const float* x = X + (size_t)r*29;
  float a[29]; float s = 0.f;
  #pragma unroll
  for (int k=0;k<29;k++){ a[k]=x[k]; s+=a[k]; }
  float mean = s*(1.0f/29.0f);
  float q = 0.f;
  #pragma unroll
  for (int k=0;k<29;k++){ float d=a[k]-mean; q+=d*d; }
  float rstd = rsqrtf(q*(1.0f/29.0f) + 1e-5f);
  float* y = Y + (size_t)r*29;
  #pragma unroll
  for (int k=0;k<29;k++) y[k] = (a[k]-mean)*rstd*g[k] + bv[k];
}

// ======================= fp32 tiled GEMM: C = A(M,K) @ W(K,N) [+bias] [+=] ======
// BM=BN=64, BK=16, 256 threads, 4x4 microtile. Requires 64|M, 64|N, 16|K.
__global__ __launch_bounds__(256) void k_gemm(const float* __restrict__ A,
    const float* __restrict__ W, const float* __restrict__ bias,
    float* __restrict__ C, int M, int N, int K, int accum)
{
  __shared__ float As[16][68];
  __shared__ float Ws[16][68];
  int tid = threadIdx.x;
  int bm = blockIdx.x*64, bn = blockIdx.y*64;
  int tr = tid >> 4, tc = tid & 15;
  int ar = tid >> 2, ac = (tid & 3)*4;       // A tile 64x16
  int wr = tid >> 4, wc4 = (tid & 15)*4;     // W tile 16x64
  float acc[4][4] = {{0}};
  for (int k0=0; k0<K; k0+=16){
    float4 av = *(const float4*)&A[(size_t)(bm+ar)*K + k0 + ac];
    As[ac+0][ar]=av.x; As[ac+1][ar]=av.y; As[ac+2][ar]=av.z; As[ac+3][ar]=av.w;
    float4 wv = *(const float4*)&W[(size_t)(k0+wr)*N + bn + wc4];
    *(float4*)&Ws[wr][wc4] = wv;
    __syncthreads();
    #pragma unroll
    for (int k=0;k<16;k++){
      float4 am = *(const float4*)&As[k][tr*4];
      float4 wn = *(const float4*)&Ws[k][tc*4];
      float amv[4]={am.x,am.y,am.z,am.w};
      float wnv[4]={wn.x,wn.y,wn.z,wn.w};
      #pragma unroll
      for (int i=0;i<4;i++)
        #pragma unroll
        for (int j=0;j<4;j++) acc[i][j] += amv[i]*wnv[j];
    }
    __syncthreads();
  }
  #pragma unroll
  for (int i=0;i<4;i++){
    size_t off = (size_t)(bm+tr*4+i)*N + bn + tc*4;
    #pragma unroll
    for (int j=0;j<4;j++){
      float v = acc[i][j];
      if (bias) v += bias[bn+tc*4+j];
      if (accum) C[off+j] += v; else C[off+j] = v;
    }
  }
}

// ======================= GEGLU elementwise (latent FF, F=2048) =======================
__global__ __launch_bounds__(256) void k_geglu(const float* __restrict__ ff1, float* __restrict__ out)
{
  int idx = blockIdx.x*256 + threadIdx.x;    // < 2048*2048 exactly
  int m = idx >> 11, f = idx & 2047;
  float a = ff1[(size_t)m*4096 + f];
  float g = ff1[(size_t)m*4096 + 2048 + f];
  out[idx] = a * gelu_exact(g);
}

// ======================= tiled two-pass attention, m=256 keys, dh=64 ===============
// Block: 256 threads, 32 query rows. Q:(B,n,heads*64)[q_rs], K/V rows stride kv_rs.
__global__ __launch_bounds__(256) void k_attn(
    const float* __restrict__ Q, const float* __restrict__ Kb, const float* __restrict__ Vb,
    float* __restrict__ O, int n, int heads, int q_rs, int kv_rs, int o_rs, float scale)
{
  __shared__ float Sq[32*64];     // q block, pre-scaled
  __shared__ float Kt[64*68];     // K tile transposed [d][j] (pad 68); aliased as Vs[64*64]
  __shared__ float S [32*256];    // scores -> probabilities
  int tid = threadIdx.x;
  int lane = tid & 63, w = tid >> 6;
  int tc = tid & 15, tr = tid >> 4;
  int bpb = n >> 5;
  int bh = blockIdx.x / bpb;
  int i0 = (blockIdx.x - bh*bpb) << 5;
  int h = bh % heads, b = bh / heads;
  size_t qbase = ((size_t)(b*n + i0))*q_rs + h*64;
  for (int idx=tid; idx<32*64; idx+=256){
    int row = idx >> 6, d = idx & 63;
    Sq[idx] = Q[qbase + (size_t)row*q_rs + d] * scale;
  }
  size_t kvbase = ((size_t)(b*256))*kv_rs + h*64;
  // ---- pass 1: scores ----
  for (int t=0;t<4;t++){
    if (t) __syncthreads();
    for (int idx=tid; idx<64*64; idx+=256){
      int d = idx & 63, j = idx >> 6;
      Kt[d*68 + j] = Kb[kvbase + (size_t)(t*64 + j)*kv_rs + d];
    }
    __syncthreads();
    float sc0[4]={0,0,0,0}, sc1[4]={0,0,0,0};
    #pragma unroll 8
    for (int d=0; d<64; d++){
      float4 kj = *(const float4*)&Kt[d*68 + tc*4];
      float a0 = Sq[(tr*2+0)*64 + d];
      float a1 = Sq[(tr*2+1)*64 + d];
      sc0[0]+=a0*kj.x; sc0[1]+=a0*kj.y; sc0[2]+=a0*kj.z; sc0[3]+=a0*kj.w;
      sc1[0]+=a1*kj.x; sc1[1]+=a1*kj.y; sc1[2]+=a1*kj.z; sc1[3]+=a1*kj.w;
    }
    *(float4*)&S[(tr*2+0)*256 + t*64 + tc*4] = make_float4(sc0[0],sc0[1],sc0[2],sc0[3]);
    *(float4*)&S[(tr*2+1)*256 + t*64 + tc*4] = make_float4(sc1[0],sc1[1],sc1[2],sc1[3]);
  }
  // ---- softmax (wave-local rows: wave w owns rows 8w..8w+7) ----
  for (int r=0;r<8;r++){
    float* Sr = S + (w*8+r)*256;
    float v0=Sr[lane], v1=Sr[64+lane], v2=Sr[128+lane], v3=Sr[192+lane];
    float mx = fmaxf(fmaxf(v0,v1),fmaxf(v2,v3));
    #pragma unroll
    for (int off=32; off; off>>=1) mx = fmaxf(mx, __shfl_xor(mx, off));
    float e0=__expf(v0-mx), e1=__expf(v1-mx), e2=__expf(v2-mx), e3=__expf(v3-mx);
    float ss = e0+e1+e2+e3;
    #pragma unroll
    for (int off=32; off; off>>=1) ss += __shfl_xor(ss, off);
    float inv = 1.0f/ss;
    Sr[lane]=e0*inv; Sr[64+lane]=e1*inv; Sr[128+lane]=e2*inv; Sr[192+lane]=e3*inv;
  }
  // ---- pass 2: P @ V ----
  float o0[4]={0,0,0,0}, o1[4]={0,0,0,0};
  float* Vs = Kt;   // reuse (64*64 <= 64*68)
  for (int t=0;t<4;t++){
    __syncthreads();            // all waves done reading Kt / previous Vs
    for (int idx=tid; idx<64*64; idx+=256){
      int d = idx & 63, j = idx >> 6;
      Vs[j*64 + d] = Vb[kvbase + (size_t)(t*64 + j)*kv_rs + d];
    }
    __syncthreads();
    #pragma unroll 8
    for (int j=0;j<64;j++){
      float4 vv = *(const float4*)&Vs[j*64 + tc*4];
      float p0 = S[(tr*2+0)*256 + t*64 + j];
      float p1 = S[(tr*2+1)*256 + t*64 + j];
      o0[0]+=p0*vv.x; o0[1]+=p0*vv.y; o0[2]+=p0*vv.z; o0[3]+=p0*vv.w;
      o1[0]+=p1*vv.x; o1[1]+=p1*vv.y; o1[2]+=p1*vv.z; o1[3]+=p1*vv.w;
    }
  }
  size_t obase = ((size_t)(b*n + i0))*o_rs + h*64;
  *(float4*)&O[obase + (size_t)(tr*2+0)*o_rs + tc*4] = make_float4(o0[0],o0[1],o0[2],o0[3]);
  *(float4*)&O[obase + (size_t)(tr*2+1)*o_rs + tc*4] = make_float4(o1[0],o1[1],o1[2],o1[3]);
}

// ======================= small-K row GEMM: out(r,N) = A(r,KT) @ W [+bias] [+=] =====
template<int KT>
__global__ __launch_bounds__(256) void k_rowgemm(const float* __restrict__ A,
    const float* __restrict__ Wg, const float* __restrict__ bias,
    float* __restrict__ out, int rows, int N, int accum)
{
  extern __shared__ float sw[];
  float* sb = sw + KT*N;
  for (int idx=threadIdx.x; idx<KT*N; idx+=256) sw[idx]=Wg[idx];
  if (bias) for (int idx=threadIdx.x; idx<N; idx+=256) sb[idx]=bias[idx];
  __syncthreads();
  int r = blockIdx.x*256 + threadIdx.x;
  if (r >= rows) return;
  float a[KT];
  const float* Ar = A + (size_t)r*KT;
  #pragma unroll
  for (int k=0;k<KT;k++) a[k]=Ar[k];
  float* op = out + (size_t)r*N;
  for (int nn=0; nn<N; nn++){
    float s = bias ? sb[nn] : 0.f;
    #pragma unroll
    for (int k=0;k<KT;k++) s += a[k]*sw[k*N+nn];
    if (accum) op[nn] += s; else op[nn] = s;
  }
}

// ======================= fused cross FF: data += GEGLU(qn@W1+b1) @ W2 + b2 ========
__global__ __launch_bounds__(256) void k_cross_ff(const float* __restrict__ qn,
    const float* __restrict__ W1, const float* __restrict__ b1,
    const float* __restrict__ W2, const float* __restrict__ b2,
    float* __restrict__ data)
{
  __shared__ float s1[29*232];
  __shared__ float sb1[232];
  __shared__ float s2[116*29];
  __shared__ float sb2[29];
  for (int idx=threadIdx.x; idx<29*232; idx+=256) s1[idx]=W1[idx];
  for (int idx=threadIdx.x; idx<232;    idx+=256) sb1[idx]=b1[idx];
  for (int idx=threadIdx.x; idx<116*29; idx+=256) s2[idx]=W2[idx];
  for (int idx=threadIdx.x; idx<29;     idx+=256) sb2[idx]=b2[idx];
  __syncthreads();
  int r = blockIdx.x*256 + threadIdx.x;      // rows = 131072 exactly
  float a[29];
  const float* qr = qn + (size_t)r*29;
  #pragma unroll
  for (int k=0;k<29;k++) a[k]=qr[k];
  float acc[29];
  #pragma unroll
  for (int nn=0;nn<29;nn++) acc[nn]=sb2[nn];
  for (int f=0; f<116; f++){
    float sa = sb1[f], sg = sb1[116+f];
    #pragma unroll
    for (int k=0;k<29;k++){ float ak=a[k]; sa += ak*s1[k*232+f]; sg += ak*s1[k*232+116+f]; }
    float gf = sa * gelu_exact(sg);
    #pragma unroll
    for (int nn=0;nn<29;nn++) acc[nn] += gf*s2[f*29+nn];
  }
  float* dr = data + (size_t)r*29;
  #pragma unroll
  for (int nn=0;nn<29;nn++) dr[nn] += acc[nn];
}

// ======================= output: data[..., :3] =======================
__global__ __launch_bounds__(256) void k_out(const float* __restrict__ data, float* __restrict__ out)
{
  int idx = blockIdx.x*256 + threadIdx.x;    // < 393216 exactly
  int p = idx/3, c = idx - p*3;
  out[idx] = data[(size_t)p*29 + c];
}

// =====================================================================
extern "C" void kernel_launch(void* const* d_in, const int* in_sizes, int n_in,
                              void* d_out, int out_size, void* d_ws, size_t ws_size,
                              hipStream_t stream) {
  const float* x        = (const float*)d_in[0];
  const float* latents  = (const float*)d_in[1];
  const float* W_l2l    = (const float*)d_in[2];
  const float* b_l2l    = (const float*)d_in[3];
  const float* ca_ln_q_g= (const float*)d_in[4];
  const float* ca_ln_q_b= (const float*)d_in[5];
  const float* ca_ln_c_g= (const float*)d_in[6];
  const float* ca_ln_c_b= (const float*)d_in[7];
  const float* ca_Wq    = (const float*)d_in[8];
  const float* ca_Wkv   = (const float*)d_in[9];
  const float* ca_Wo    = (const float*)d_in[10];
  const float* ca_bo    = (const float*)d_in[11];
  const float* cf_ln_g  = (const float*)d_in[12];
  const float* cf_ln_b  = (const float*)d_in[13];
  const float* cf_W1    = (const float*)d_in[14];
  const float* cf_b1    = (const float*)d_in[15];
  const float* cf_W2    = (const float*)d_in[16];
  const float* cf_b2    = (const float*)d_in[17];
  const float* la_ln_g  = (const float*)d_in[18];
  const float* la_ln_b  = (const float*)d_in[19];
  const float* la_Wq    = (const float*)d_in[20];
  const float* la_Wkv   = (const float*)d_in[21];
  const float* la_Wo    = (const float*)d_in[22];
  const float* la_bo    = (const float*)d_in[23];
  const float* lf_ln_g  = (const float*)d_in[24];
  const float* lf_ln_b  = (const float*)d_in[25];
  const float* lf_W1    = (const float*)d_in[26];
  const float* lf_b1    = (const float*)d_in[27];
  const float* lf_W2    = (const float*)d_in[28];
  const float* lf_b2    = (const float*)d_in[29];

  float* ws   = (float*)d_ws;
  // workspace layout (floats); R region time-shared between phases
  float* data = ws;                     // 3,801,088  (8*16384*29)
  float* qn   = data + 3801088;         // 3,801,088
  float* R    = qn   + 3801088;         // 16,777,216
  float* kv_c = R    + 16777216;        //   262,144  (2048*128)
  float* lat  = kv_c + 262144;          // 1,048,576  (8*256*512)
  float* latn = lat  + 1048576;         // 1,048,576
  float* q_l  = latn + 1048576;         // 1,048,576
  float* kv_l = q_l  + 1048576;         // 2,097,152  (2048*1024)
  float* ao_l = kv_l + 2097152;         // 1,048,576
  // aliases inside R (temporally disjoint):
  float* ff1  = R;                      // 2048*4096 (latent FF phase)
  float* gg   = R + 8388608;            // 2048*2048 (latent FF phase)
  float* q_c  = R;                      // 131072*64 (cross-attn phase)
  float* ao_c = R + 8388608;            // 131072*64 (cross-attn phase)

  k_encode<<<64, 256, 0, stream>>>(data);
  k_l2l   <<<512, 256, 0, stream>>>(x, W_l2l, b_l2l, latents, lat);

  for (int i=0;i<4;i++){
    // ---- latent self-attention ----
    k_ln512<<<2048,256,0,stream>>>(lat, la_ln_g+i*512, la_ln_b+i*512, latn);
    k_gemm <<<dim3(32,8), 256,0,stream>>>(latn, la_Wq +(size_t)i*512*512,  nullptr, q_l,  2048, 512, 512, 0);
    k_gemm <<<dim3(32,16),256,0,stream>>>(latn, la_Wkv+(size_t)i*512*1024, nullptr, kv_l, 2048,1024, 512, 0);
    k_attn <<<8*8*(256/32),256,0,stream>>>(q_l, kv_l, kv_l+512, ao_l, 256, 8, 512, 1024, 512, 0.125f);
    k_gemm <<<dim3(32,8), 256,0,stream>>>(ao_l, la_Wo +(size_t)i*512*512, la_bo+i*512, lat, 2048, 512, 512, 1);
    // ---- latent GEGLU FF ----
    k_ln512<<<2048,256,0,stream>>>(lat, lf_ln_g+i*512, lf_ln_b+i*512, latn);
    k_gemm <<<dim3(32,64),256,0,stream>>>(latn, lf_W1+(size_t)i*512*4096, lf_b1+i*4096, ff1, 2048, 4096, 512, 0);
    k_geglu<<<16384,256,0,stream>>>(ff1, gg);
    k_gemm <<<dim3(32,8), 256,0,stream>>>(gg, lf_W2+(size_t)i*2048*512, lf_b2+i*512, lat, 2048, 512, 2048, 1);
    // ---- cross-attention (data <- lat) ----
    k_ln29 <<<512,256,0,stream>>>(data, ca_ln_q_g+i*29, ca_ln_q_b+i*29, qn);
    k_ln512<<<2048,256,0,stream>>>(lat, ca_ln_c_g+i*512, ca_ln_c_b+i*512, latn);
    k_gemm <<<dim3(32,2), 256,0,stream>>>(latn, ca_Wkv+(size_t)i*512*128, nullptr, kv_c, 2048, 128, 512, 0);
    k_rowgemm<29><<<512,256,(29*64+64)*4,stream>>>(qn, ca_Wq+(size_t)i*29*64, nullptr, q_c, 131072, 64, 0);
    k_attn <<<8*(16384/32),256,0,stream>>>(q_c, kv_c, kv_c+64, ao_c, 16384, 1, 64, 128, 64, 0.125f);
    k_rowgemm<64><<<512,256,(64*29+29)*4,stream>>>(ao_c, ca_Wo+(size_t)i*64*29, ca_bo+i*29, data, 131072, 29, 1);
    // ---- cross GEGLU FF (fully fused) ----
    k_ln29 <<<512,256,0,stream>>>(data, cf_ln_g+i*29, cf_ln_b+i*29, qn);
    k_cross_ff<<<512,256,0,stream>>>(qn, cf_W1+(size_t)i*29*232, cf_b1+i*232,
                                     cf_W2+(size_t)i*116*29, cf_b2+i*29, data);
  }

  k_out<<<1536,256,0,stream>>>(data, (float*)d_out);
}

// Round 3
// 3526.218 us; speedup vs baseline: 1.2429x; 1.2429x over previous
//
#include <hip/hip_runtime.h>
#include <math.h>

#define DEV __device__ __forceinline__

DEV float gelu_exact(float x){ return 0.5f*x*(1.0f+erff(x*0.70710678118654752440f)); }

// ---- bf16 helpers (raw ushort storage, RNE convert) ----
DEV unsigned short f2bf(float x){
  union { float f; unsigned int u; } v; v.f = x;
  unsigned int r = v.u + 0x7FFFu + ((v.u >> 16) & 1u);
  return (unsigned short)(r >> 16);
}
DEV float bf2f(unsigned short b){ union { unsigned int u; float f; } v; v.u = ((unsigned int)b)<<16; return v.f; }
DEV void split2(float x, unsigned short& h, unsigned short& l){
  h = f2bf(x); l = f2bf(x - bf2f(h));
}

typedef __bf16 bf16x8 __attribute__((ext_vector_type(8)));
typedef float  f32x4  __attribute__((ext_vector_type(4)));

DEV void gload16(const void* g, void* lds){
  __builtin_amdgcn_global_load_lds((const __attribute__((address_space(1))) unsigned int*)g,
                                   (__attribute__((address_space(3))) unsigned int*)lds, 16, 0, 0);
}

// ======================= Fourier-encode data grid =======================
__global__ __launch_bounds__(256) void k_encode(float* __restrict__ data)
{
  int p = blockIdx.x*256 + threadIdx.x;      // 0..16383
  int hh = p >> 7, ww = p & 127;
  float y = -1.0f + hh*(2.0f/127.0f);
  float x = -1.0f + ww*(2.0f/127.0f);
  float e[26];
  #pragma unroll
  for (int i=0;i<6;i++){
    float sc = exp2f(1.0f + i*0.26438561897747245f) * 3.14159265358979323846f;
    e[i]     = sinf(y*sc);
    e[6+i]   = cosf(y*sc);
    e[13+i]  = sinf(x*sc);
    e[19+i]  = cosf(x*sc);
  }
  e[12]=y; e[25]=x;
  #pragma unroll
  for (int b=0;b<8;b++){
    float* dr = data + ((size_t)(b*16384 + p))*29;
    dr[0]=0.f; dr[1]=0.f; dr[2]=0.f;
    #pragma unroll
    for (int c=0;c<26;c++) dr[3+c]=e[c];
  }
}

// ======================= lat = x @ W_l2l + b + latents =======================
__global__ __launch_bounds__(256) void k_l2l(const float* __restrict__ x,
    const float* __restrict__ Wl, const float* __restrict__ bl,
    const float* __restrict__ latents, float* __restrict__ lat)
{
  __shared__ float xs[8*512];
  int tid = threadIdx.x;
  for (int idx=tid; idx<4096; idx+=256) xs[idx]=x[idx];
  __syncthreads();
  int nIdx = blockIdx.x*256 + tid;
  float acc[8] = {0,0,0,0,0,0,0,0};
  for (int k=0;k<512;k++){
    float w = Wl[(size_t)k*131072 + nIdx];
    #pragma unroll
    for (int m=0;m<8;m++) acc[m] += xs[m*512+k]*w;
  }
  float add = bl[nIdx] + latents[nIdx];
  #pragma unroll
  for (int m=0;m<8;m++) lat[(size_t)m*131072 + nIdx] = acc[m] + add;
}

// ======================= LayerNorm D=512 -> split bf16 hi/lo =======================
__global__ __launch_bounds__(256) void k_ln512s(const float* __restrict__ X,
    const float* __restrict__ g, const float* __restrict__ bv,
    unsigned short* __restrict__ hi, unsigned short* __restrict__ lo)
{
  __shared__ float red[8];
  int row = blockIdx.x, tid = threadIdx.x;
  const float* x = X + (size_t)row*512;
  float v0 = x[tid], v1 = x[tid+256];
  float s = v0+v1;
  #pragma unroll
  for (int off=32; off; off>>=1) s += __shfl_xor(s, off);
  if ((tid&63)==0) red[tid>>6] = s;
  __syncthreads();
  float mean = (red[0]+red[1]+red[2]+red[3]) * (1.0f/512.0f);
  float d0 = v0-mean, d1 = v1-mean;
  float q = d0*d0 + d1*d1;
  #pragma unroll
  for (int off=32; off; off>>=1) q += __shfl_xor(q, off);
  if ((tid&63)==0) red[4+(tid>>6)] = q;
  __syncthreads();
  float var = (red[4]+red[5]+red[6]+red[7]) * (1.0f/512.0f);
  float rstd = rsqrtf(var + 1e-5f);
  float y0 = d0*rstd*g[tid]     + bv[tid];
  float y1 = d1*rstd*g[tid+256] + bv[tid+256];
  unsigned short h,l;
  split2(y0,h,l); hi[(size_t)row*512+tid]=h;     lo[(size_t)row*512+tid]=l;
  split2(y1,h,l); hi[(size_t)row*512+tid+256]=h; lo[(size_t)row*512+tid+256]=l;
}

// ======================= LayerNorm D=29 =======================
__global__ __launch_bounds__(256) void k_ln29(const float* __restrict__ X,
    const float* __restrict__ g, const float* __restrict__ bv, float* __restrict__ Y)
{
  int r = blockIdx.x*256 + threadIdx.x;
  const float* x = X + (size_t)r*29;
  float a[29]; float s = 0.f;
  #pragma unroll
  for (int k=0;k<29;k++){ a[k]=x[k]; s+=a[k]; }
  float mean = s*(1.0f/29.0f);
  float q = 0.f;
  #pragma unroll
  for (int k=0;k<29;k++){ float d=a[k]-mean; q+=d*d; }
  float rstd = rsqrtf(q*(1.0f/29.0f) + 1e-5f);
  float* y = Y + (size_t)r*29;
  #pragma unroll
  for (int k=0;k<29;k++) y[k] = (a[k]-mean)*rstd*g[k] + bv[k];
}

// ======================= weight split+transpose: W(KxN) -> Wt hi/lo (NxK) ==========
__global__ __launch_bounds__(256) void k_split_w(const float* __restrict__ W,
    unsigned short* __restrict__ hi, int K, int N)
{
  __shared__ float t[64][65];
  unsigned short* lo = hi + (size_t)N*K;
  int k0 = blockIdx.x*64, n0 = blockIdx.y*64;
  int tid = threadIdx.x;
  #pragma unroll
  for (int i=0;i<4;i++){
    int s = tid + 256*i;
    int r = s >> 4, c4 = (s & 15)*4;
    float4 v = *(const float4*)&W[(size_t)(k0+r)*N + n0 + c4];
    t[r][c4+0]=v.x; t[r][c4+1]=v.y; t[r][c4+2]=v.z; t[r][c4+3]=v.w;
  }
  __syncthreads();
  #pragma unroll
  for (int i=0;i<4;i++){
    int s = tid + 256*i;
    int n = s >> 4, kc = (s & 15)*4;
    size_t o = (size_t)(n0+n)*K + k0 + kc;
    #pragma unroll
    for (int j=0;j<4;j++){
      unsigned short h,l; split2(t[kc+j][n], h, l);
      hi[o+j]=h; lo[o+j]=l;
    }
  }
}

// ======================= split-bf16 MFMA GEMM ==================================
// C(MxN) = [Ahi+Alo](MxK) @ [Bhi+Blo](KxN),  B given transposed NxK.
// A buffers: hi matrix then lo matrix stacked (each M*K).  B: hi then lo (each N*K).
// 128x128 tile, BK=32, 256 thr (4 waves, each 64x64 via 4x4 of 16x16x32 mfma).
// 3 mfma per tile-pair: hi*hi + hi*lo + lo*hi.  Ksplit>1 => accum must be 1 (atomicAdd).
__global__ __launch_bounds__(256) void k_mfma(
    const unsigned short* __restrict__ Ahi, const unsigned short* __restrict__ Bhi,
    const float* __restrict__ bias, float* __restrict__ C,
    int M, int N, int K, int Ksplit, int accum)
{
  __shared__ unsigned short sm[4*128*32];   // AH | AL | BH | BL, each 128 rows x 32 (chunk-swizzled)
  int tid = threadIdx.x, lane = tid & 63, w = tid >> 6;
  int bm = blockIdx.x*128, bn = blockIdx.y*128;
  int Ks = K / Ksplit;
  int kbeg = blockIdx.z * Ks;
  const unsigned short* tsrc;
  if      (w==0) tsrc = Ahi + (size_t)bm*K;
  else if (w==1) tsrc = Ahi + (size_t)M*K + (size_t)bm*K;
  else if (w==2) tsrc = Bhi + (size_t)bn*K;
  else           tsrc = Bhi + (size_t)N*K + (size_t)bn*K;
  unsigned short* mylds = sm + w*4096;
  f32x4 acc[4][4];
  #pragma unroll
  for(int i=0;i<4;i++)
    #pragma unroll
    for(int j=0;j<4;j++) acc[i][j] = (f32x4){0.f,0.f,0.f,0.f};
  int wm = (w>>1)*64, wn = (w&1)*64;
  int frow = lane & 15, fq = lane >> 4;
  for (int k0 = kbeg; k0 < kbeg + Ks; k0 += 32){
    #pragma unroll
    for (int j=0;j<8;j++){
      int idx = j*64 + lane;
      int row = idx >> 2, qp = idx & 3;
      int q = (qp - row) & 3;                       // chunk swizzle (inverse)
      gload16(tsrc + (size_t)row*K + k0 + q*8, mylds + j*512);
    }
    __syncthreads();
    bf16x8 ah[4], al[4];
    #pragma unroll
    for (int mt=0;mt<4;mt++){
      int row = wm + mt*16 + frow;
      int off = row*32 + ((fq + row)&3)*8;
      ah[mt] = *(const bf16x8*)(sm + off);
      al[mt] = *(const bf16x8*)(sm + 4096 + off);
    }
    #pragma unroll
    for (int nt=0;nt<4;nt++){
      int rowb = wn + nt*16 + frow;
      int offb = rowb*32 + ((fq + rowb)&3)*8;
      bf16x8 bh = *(const bf16x8*)(sm + 2*4096 + offb);
      bf16x8 bl = *(const bf16x8*)(sm + 3*4096 + offb);
      #pragma unroll
      for (int mt=0;mt<4;mt++){
        acc[mt][nt] = __builtin_amdgcn_mfma_f32_16x16x32_bf16(ah[mt], bh, acc[mt][nt], 0,0,0);
        acc[mt][nt] = __builtin_amdgcn_mfma_f32_16x16x32_bf16(ah[mt], bl, acc[mt][nt], 0,0,0);
        acc[mt][nt] = __builtin_amdgcn_mfma_f32_16x16x32_bf16(al[mt], bh, acc[mt][nt], 0,0,0);
      }
    }
    __syncthreads();
  }
  #pragma unroll
  for (int mt=0;mt<4;mt++){
    #pragma unroll
    for (int nt=0;nt<4;nt++){
      int col = bn + wn + nt*16 + frow;
      float bv = (bias && blockIdx.z==0) ? bias[col] : 0.f;
      #pragma unroll
      for (int r=0;r<4;r++){
        int row = bm + wm + mt*16 + fq*4 + r;
        float v = acc[mt][nt][r] + bv;
        if (accum) atomicAdd(&C[(size_t)row*N + col], v);
        else       C[(size_t)row*N + col] = v;
      }
    }
  }
}

// ======================= GEGLU -> split bf16 (latent FF) =======================
__global__ __launch_bounds__(256) void k_geglus(const float* __restrict__ ff1,
    unsigned short* __restrict__ hi, unsigned short* __restrict__ lo)
{
  int idx = blockIdx.x*256 + threadIdx.x;    // < 2048*2048
  int m = idx >> 11, f = idx & 2047;
  float a = ff1[(size_t)m*4096 + f];
  float g = ff1[(size_t)m*4096 + 2048 + f];
  unsigned short h,l; split2(a * gelu_exact(g), h, l);
  hi[idx]=h; lo[idx]=l;
}

// ======================= tiled two-pass attention, m=256 keys, dh=64 ===============
// If Ohi != null: write split bf16 hi/lo (stride o_rs) instead of fp32 O.
// NOTE: O may alias Q (block reads its Q rows into LDS before any O write).
__global__ __launch_bounds__(256) void k_attn(
    const float* __restrict__ Q, const float* __restrict__ Kb, const float* __restrict__ Vb,
    float* __restrict__ O, int n, int heads, int q_rs, int kv_rs, int o_rs, float scale,
    unsigned short* __restrict__ Ohi, unsigned short* __restrict__ Olo)
{
  __shared__ float Sq[32*64];
  __shared__ float Kt[64*68];
  __shared__ float S [32*260];    // padded stride 260: row-to-row bank shift of 4
  int tid = threadIdx.x;
  int lane = tid & 63, w = tid >> 6;
  int tc = tid & 15, tr = tid >> 4;
  int bpb = n >> 5;
  int bh = blockIdx.x / bpb;
  int i0 = (blockIdx.x - bh*bpb) << 5;
  int h = bh % heads, b = bh / heads;
  size_t qbase = ((size_t)(b*n + i0))*q_rs + h*64;
  for (int idx=tid; idx<32*64; idx+=256){
    int row = idx >> 6, d = idx & 63;
    Sq[idx] = Q[qbase + (size_t)row*q_rs + d] * scale;
  }
  size_t kvbase = ((size_t)(b*256))*kv_rs + h*64;
  for (int t=0;t<4;t++){
    if (t) __syncthreads();
    for (int idx=tid; idx<64*64; idx+=256){
      int d = idx & 63, j = idx >> 6;
      Kt[d*68 + j] = Kb[kvbase + (size_t)(t*64 + j)*kv_rs + d];
    }
    __syncthreads();
    float sc0[4]={0,0,0,0}, sc1[4]={0,0,0,0};
    #pragma unroll 8
    for (int d=0; d<64; d++){
      float4 kj = *(const float4*)&Kt[d*68 + tc*4];
      float a0 = Sq[(tr*2+0)*64 + d];
      float a1 = Sq[(tr*2+1)*64 + d];
      sc0[0]+=a0*kj.x; sc0[1]+=a0*kj.y; sc0[2]+=a0*kj.z; sc0[3]+=a0*kj.w;
      sc1[0]+=a1*kj.x; sc1[1]+=a1*kj.y; sc1[2]+=a1*kj.z; sc1[3]+=a1*kj.w;
    }
    *(float4*)&S[(tr*2+0)*260 + t*64 + tc*4] = make_float4(sc0[0],sc0[1],sc0[2],sc0[3]);
    *(float4*)&S[(tr*2+1)*260 + t*64 + tc*4] = make_float4(sc1[0],sc1[1],sc1[2],sc1[3]);
  }
  for (int r=0;r<8;r++){
    float* Sr = S + (w*8+r)*260;
    float v0=Sr[lane], v1=Sr[64+lane], v2=Sr[128+lane], v3=Sr[192+lane];
    float mx = fmaxf(fmaxf(v0,v1),fmaxf(v2,v3));
    #pragma unroll
    for (int off=32; off; off>>=1) mx = fmaxf(mx, __shfl_xor(mx, off));
    float e0=__expf(v0-mx), e1=__expf(v1-mx), e2=__expf(v2-mx), e3=__expf(v3-mx);
    float ss = e0+e1+e2+e3;
    #pragma unroll
    for (int off=32; off; off>>=1) ss += __shfl_xor(ss, off);
    float inv = 1.0f/ss;
    Sr[lane]=e0*inv; Sr[64+lane]=e1*inv; Sr[128+lane]=e2*inv; Sr[192+lane]=e3*inv;
  }
  float o0[4]={0,0,0,0}, o1[4]={0,0,0,0};
  float* Vs = Kt;
  for (int t=0;t<4;t++){
    __syncthreads();
    for (int idx=tid; idx<64*64; idx+=256){
      int d = idx & 63, j = idx >> 6;
      Vs[j*64 + d] = Vb[kvbase + (size_t)(t*64 + j)*kv_rs + d];
    }
    __syncthreads();
    #pragma unroll 8
    for (int j=0;j<64;j++){
      float4 vv = *(const float4*)&Vs[j*64 + tc*4];
      float p0 = S[(tr*2+0)*260 + t*64 + j];
      float p1 = S[(tr*2+1)*260 + t*64 + j];
      o0[0]+=p0*vv.x; o0[1]+=p0*vv.y; o0[2]+=p0*vv.z; o0[3]+=p0*vv.w;
      o1[0]+=p1*vv.x; o1[1]+=p1*vv.y; o1[2]+=p1*vv.z; o1[3]+=p1*vv.w;
    }
  }
  size_t obase = ((size_t)(b*n + i0))*o_rs + h*64;
  if (Ohi){
    #pragma unroll
    for (int j=0;j<4;j++){
      unsigned short hh,ll;
      split2(o0[j],hh,ll);
      Ohi[obase + (size_t)(tr*2+0)*o_rs + tc*4+j]=hh; Olo[obase + (size_t)(tr*2+0)*o_rs + tc*4+j]=ll;
      split2(o1[j],hh,ll);
      Ohi[obase + (size_t)(tr*2+1)*o_rs + tc*4+j]=hh; Olo[obase + (size_t)(tr*2+1)*o_rs + tc*4+j]=ll;
    }
  } else {
    *(float4*)&O[obase + (size_t)(tr*2+0)*o_rs + tc*4] = make_float4(o0[0],o0[1],o0[2],o0[3]);
    *(float4*)&O[obase + (size_t)(tr*2+1)*o_rs + tc*4] = make_float4(o1[0],o1[1],o1[2],o1[3]);
  }
}

// ======================= small-K row GEMM =======================
template<int KT>
__global__ __launch_bounds__(256) void k_rowgemm(const float* __restrict__ A,
    const float* __restrict__ Wg, const float* __restrict__ bias,
    float* __restrict__ out, int rows, int N, int accum)
{
  extern __shared__ float sw[];
  float* sb = sw + KT*N;
  for (int idx=threadIdx.x; idx<KT*N; idx+=256) sw[idx]=Wg[idx];
  if (bias) for (int idx=threadIdx.x; idx<N; idx+=256) sb[idx]=bias[idx];
  __syncthreads();
  int r = blockIdx.x*256 + threadIdx.x;
  if (r >= rows) return;
  float a[KT];
  const float* Ar = A + (size_t)r*KT;
  #pragma unroll
  for (int k=0;k<KT;k++) a[k]=Ar[k];
  float* op = out + (size_t)r*N;
  for (int nn=0; nn<N; nn++){
    float s = bias ? sb[nn] : 0.f;
    #pragma unroll
    for (int k=0;k<KT;k++) s += a[k]*sw[k*N+nn];
    if (accum) op[nn] += s; else op[nn] = s;
  }
}

// ======================= fused cross FF =======================
__global__ __launch_bounds__(256) void k_cross_ff(const float* __restrict__ qn,
    const float* __restrict__ W1, const float* __restrict__ b1,
    const float* __restrict__ W2, const float* __restrict__ b2,
    float* __restrict__ data)
{
  __shared__ float s1[29*232];
  __shared__ float sb1[232];
  __shared__ float s2[116*29];
  __shared__ float sb2[29];
  for (int idx=threadIdx.x; idx<29*232; idx+=256) s1[idx]=W1[idx];
  for (int idx=threadIdx.x; idx<232;    idx+=256) sb1[idx]=b1[idx];
  for (int idx=threadIdx.x; idx<116*29; idx+=256) s2[idx]=W2[idx];
  for (int idx=threadIdx.x; idx<29;     idx+=256) sb2[idx]=b2[idx];
  __syncthreads();
  int r = blockIdx.x*256 + threadIdx.x;
  float a[29];
  const float* qr = qn + (size_t)r*29;
  #pragma unroll
  for (int k=0;k<29;k++) a[k]=qr[k];
  float acc[29];
  #pragma unroll
  for (int nn=0;nn<29;nn++) acc[nn]=sb2[nn];
  for (int f=0; f<116; f++){
    float sa = sb1[f], sg = sb1[116+f];
    #pragma unroll
    for (int k=0;k<29;k++){ float ak=a[k]; sa += ak*s1[k*232+f]; sg += ak*s1[k*232+116+f]; }
    float gf = sa * gelu_exact(sg);
    #pragma unroll
    for (int nn=0;nn<29;nn++) acc[nn] += gf*s2[f*29+nn];
  }
  float* dr = data + (size_t)r*29;
  #pragma unroll
  for (int nn=0;nn<29;nn++) dr[nn] += acc[nn];
}

// ======================= output =======================
__global__ __launch_bounds__(256) void k_out(const float* __restrict__ data, float* __restrict__ out)
{
  int idx = blockIdx.x*256 + threadIdx.x;
  int p = idx/3, c = idx - p*3;
  out[idx] = data[(size_t)p*29 + c];
}

// =====================================================================
extern "C" void kernel_launch(void* const* d_in, const int* in_sizes, int n_in,
                              void* d_out, int out_size, void* d_ws, size_t ws_size,
                              hipStream_t stream) {
  const float* x        = (const float*)d_in[0];
  const float* latents  = (const float*)d_in[1];
  const float* W_l2l    = (const float*)d_in[2];
  const float* b_l2l    = (const float*)d_in[3];
  const float* ca_ln_q_g= (const float*)d_in[4];
  const float* ca_ln_q_b= (const float*)d_in[5];
  const float* ca_ln_c_g= (const float*)d_in[6];
  const float* ca_ln_c_b= (const float*)d_in[7];
  const float* ca_Wq    = (const float*)d_in[8];
  const float* ca_Wkv   = (const float*)d_in[9];
  const float* ca_Wo    = (const float*)d_in[10];
  const float* ca_bo    = (const float*)d_in[11];
  const float* cf_ln_g  = (const float*)d_in[12];
  const float* cf_ln_b  = (const float*)d_in[13];
  const float* cf_W1    = (const float*)d_in[14];
  const float* cf_b1    = (const float*)d_in[15];
  const float* cf_W2    = (const float*)d_in[16];
  const float* cf_b2    = (const float*)d_in[17];
  const float* la_ln_g  = (const float*)d_in[18];
  const float* la_ln_b  = (const float*)d_in[19];
  const float* la_Wq    = (const float*)d_in[20];
  const float* la_Wkv   = (const float*)d_in[21];
  const float* la_Wo    = (const float*)d_in[22];
  const float* la_bo    = (const float*)d_in[23];
  const float* lf_ln_g  = (const float*)d_in[24];
  const float* lf_ln_b  = (const float*)d_in[25];
  const float* lf_W1    = (const float*)d_in[26];
  const float* lf_b1    = (const float*)d_in[27];
  const float* lf_W2    = (const float*)d_in[28];
  const float* lf_b2    = (const float*)d_in[29];

  float* ws   = (float*)d_ws;
  // ---- workspace layout (floats), total 26,804,224 (~107 MB) ----
  float* data = ws;                     // 3,801,088
  float* qn   = data + 3801088;         // 3,801,088
  float* R    = qn   + 3801088;         // 8,388,608  : ff1 (latent FF) | q_c==ao_c (cross)
  float* kv_c = R    + 8388608;         //   262,144
  float* lat  = kv_c + 262144;          // 1,048,576
  float* G    = lat  + 1048576;         // 4,194,304  : [q_l|kv_l|ao_s] (attn) == gg_s (FF)
  float* q_l  = G;
  float* kv_l = G + 1048576;
  unsigned short* ao_hi = (unsigned short*)(G + 3145728);  // 2048*512 hi, then lo
  unsigned short* ao_lo = ao_hi + 2048*512;
  unsigned short* gg_hi = (unsigned short*)G;              // 2048*2048 hi, then lo
  unsigned short* gg_lo = gg_hi + 2048*2048;
  unsigned short* latn_hi = (unsigned short*)(G + 4194304);// 2048*512 hi, then lo
  unsigned short* latn_lo = latn_hi + 2048*512;
  unsigned short* wsp = (unsigned short*)(G + 4194304 + 1048576); // 8,519,680 bf16
  unsigned short* wqt  = wsp;             // 512x512  hi|lo
  unsigned short* wkvt = wsp + 524288;    // 1024x512 hi|lo
  unsigned short* wot  = wsp + 1572864;   // 512x512  hi|lo
  unsigned short* w1t  = wsp + 2097152;   // 4096x512 hi|lo
  unsigned short* w2t  = wsp + 6291456;   // 512x2048 hi|lo
  unsigned short* cakvt= wsp + 8388608;   // 128x512  hi|lo
  float* ff1 = R;
  float* q_c = R;        // cross attn out aliases q_c (safe: block reads Q to LDS first)

  k_encode<<<64, 256, 0, stream>>>(data);
  k_l2l   <<<512, 256, 0, stream>>>(x, W_l2l, b_l2l, latents, lat);

  for (int i=0;i<4;i++){
    // ---- weight split+transpose into per-layer arena ----
    k_split_w<<<dim3(8,8),  256,0,stream>>>(la_Wq +(size_t)i*262144,  wqt,  512, 512);
    k_split_w<<<dim3(8,16), 256,0,stream>>>(la_Wkv+(size_t)i*524288,  wkvt, 512, 1024);
    k_split_w<<<dim3(8,8),  256,0,stream>>>(la_Wo +(size_t)i*262144,  wot,  512, 512);
    k_split_w<<<dim3(8,64), 256,0,stream>>>(lf_W1 +(size_t)i*2097152, w1t,  512, 4096);
    k_split_w<<<dim3(32,8), 256,0,stream>>>(lf_W2 +(size_t)i*1048576, w2t,  2048, 512);
    k_split_w<<<dim3(8,2),  256,0,stream>>>(ca_Wkv+(size_t)i*65536,   cakvt,512, 128);
    // ---- latent self-attention ----
    k_ln512s<<<2048,256,0,stream>>>(lat, la_ln_g+i*512, la_ln_b+i*512, latn_hi, latn_lo);
    k_mfma<<<dim3(16,4,1),256,0,stream>>>(latn_hi, wqt,  nullptr, q_l,  2048, 512, 512, 1, 0);
    k_mfma<<<dim3(16,8,1),256,0,stream>>>(latn_hi, wkvt, nullptr, kv_l, 2048,1024, 512, 1, 0);
    // blocks = B(8) * heads(8) * (n/32 = 8) = 512   <-- R2 bug was 64
    k_attn<<<512,256,0,stream>>>(q_l, kv_l, kv_l+512, nullptr, 256, 8, 512, 1024, 512, 0.125f, ao_hi, ao_lo);
    k_mfma<<<dim3(16,4,2),256,0,stream>>>(ao_hi, wot, la_bo+i*512, lat, 2048, 512, 512, 2, 1);
    // ---- latent GEGLU FF ----
    k_ln512s<<<2048,256,0,stream>>>(lat, lf_ln_g+i*512, lf_ln_b+i*512, latn_hi, latn_lo);
    k_mfma<<<dim3(16,32,1),256,0,stream>>>(latn_hi, w1t, lf_b1+i*4096, ff1, 2048, 4096, 512, 1, 0);
    k_geglus<<<16384,256,0,stream>>>(ff1, gg_hi, gg_lo);
    k_mfma<<<dim3(16,4,4),256,0,stream>>>(gg_hi, w2t, lf_b2+i*512, lat, 2048, 512, 2048, 4, 1);
    // ---- cross-attention (data <- lat) ----
    k_ln29 <<<512,256,0,stream>>>(data, ca_ln_q_g+i*29, ca_ln_q_b+i*29, qn);
    k_ln512s<<<2048,256,0,stream>>>(lat, ca_ln_c_g+i*512, ca_ln_c_b+i*512, latn_hi, latn_lo);
    k_mfma<<<dim3(16,1,1),256,0,stream>>>(latn_hi, cakvt, nullptr, kv_c, 2048, 128, 512, 1, 0);
    k_rowgemm<29><<<512,256,(29*64+64)*4,stream>>>(qn, ca_Wq+(size_t)i*29*64, nullptr, q_c, 131072, 64, 0);
    k_attn<<<4096,256,0,stream>>>(q_c, kv_c, kv_c+64, q_c, 16384, 1, 64, 128, 64, 0.125f, nullptr, nullptr);
    k_rowgemm<64><<<512,256,(64*29+29)*4,stream>>>(q_c, ca_Wo+(size_t)i*64*29, ca_bo+i*29, data, 131072, 29, 1);
    // ---- cross GEGLU FF (fully fused) ----
    k_ln29 <<<512,256,0,stream>>>(data, cf_ln_g+i*29, cf_ln_b+i*29, qn);
    k_cross_ff<<<512,256,0,stream>>>(qn, cf_W1+(size_t)i*29*232, cf_b1+i*232,
                                     cf_W2+(size_t)i*116*29, cf_b2+i*29, data);
  }

  k_out<<<1536,256,0,stream>>>(data, (float*)d_out);
}

// Round 4
// 2013.836 us; speedup vs baseline: 2.1762x; 1.7510x over previous
//
#include <hip/hip_runtime.h>
#include <math.h>

#define DEV __device__ __forceinline__

DEV float gelu_exact(float x){ return 0.5f*x*(1.0f+erff(x*0.70710678118654752440f)); }

DEV unsigned short f2bf(float x){
  union { float f; unsigned int u; } v; v.f = x;
  unsigned int r = v.u + 0x7FFFu + ((v.u >> 16) & 1u);
  return (unsigned short)(r >> 16);
}
DEV float bf2f(unsigned short b){ union { unsigned int u; float f; } v; v.u = ((unsigned int)b)<<16; return v.f; }
DEV void split2(float x, unsigned short& h, unsigned short& l){
  h = f2bf(x); l = f2bf(x - bf2f(h));
}

typedef __bf16 bf16x8 __attribute__((ext_vector_type(8)));
typedef float  f32x4  __attribute__((ext_vector_type(4)));

DEV void gload16(const void* g, void* lds){
  __builtin_amdgcn_global_load_lds((const __attribute__((address_space(1))) unsigned int*)g,
                                   (__attribute__((address_space(3))) unsigned int*)lds, 16, 0, 0);
}

// ======================= Fourier-encode data grid =======================
__global__ __launch_bounds__(256) void k_encode(float* __restrict__ data)
{
  int p = blockIdx.x*256 + threadIdx.x;
  int hh = p >> 7, ww = p & 127;
  float y = -1.0f + hh*(2.0f/127.0f);
  float x = -1.0f + ww*(2.0f/127.0f);
  float e[26];
  #pragma unroll
  for (int i=0;i<6;i++){
    float sc = exp2f(1.0f + i*0.26438561897747245f) * 3.14159265358979323846f;
    e[i]     = sinf(y*sc);
    e[6+i]   = cosf(y*sc);
    e[13+i]  = sinf(x*sc);
    e[19+i]  = cosf(x*sc);
  }
  e[12]=y; e[25]=x;
  #pragma unroll
  for (int b=0;b<8;b++){
    float* dr = data + ((size_t)(b*16384 + p))*29;
    dr[0]=0.f; dr[1]=0.f; dr[2]=0.f;
    #pragma unroll
    for (int c=0;c<26;c++) dr[3+c]=e[c];
  }
}

// ======================= lat = x @ W_l2l + b + latents =======================
__global__ __launch_bounds__(256) void k_l2l(const float* __restrict__ x,
    const float* __restrict__ Wl, const float* __restrict__ bl,
    const float* __restrict__ latents, float* __restrict__ lat)
{
  __shared__ float xs[8*512];
  int tid = threadIdx.x;
  for (int idx=tid; idx<4096; idx+=256) xs[idx]=x[idx];
  __syncthreads();
  int nIdx = blockIdx.x*256 + tid;
  float acc[8] = {0,0,0,0,0,0,0,0};
  for (int k=0;k<512;k++){
    float w = Wl[(size_t)k*131072 + nIdx];
    #pragma unroll
    for (int m=0;m<8;m++) acc[m] += xs[m*512+k]*w;
  }
  float add = bl[nIdx] + latents[nIdx];
  #pragma unroll
  for (int m=0;m<8;m++) lat[(size_t)m*131072 + nIdx] = acc[m] + add;
}

// ======================= LayerNorm D=512 -> split bf16 hi/lo =======================
__global__ __launch_bounds__(256) void k_ln512s(const float* __restrict__ X,
    const float* __restrict__ g, const float* __restrict__ bv,
    unsigned short* __restrict__ hi, unsigned short* __restrict__ lo)
{
  __shared__ float red[8];
  int row = blockIdx.x, tid = threadIdx.x;
  const float* x = X + (size_t)row*512;
  float v0 = x[tid], v1 = x[tid+256];
  float s = v0+v1;
  #pragma unroll
  for (int off=32; off; off>>=1) s += __shfl_xor(s, off);
  if ((tid&63)==0) red[tid>>6] = s;
  __syncthreads();
  float mean = (red[0]+red[1]+red[2]+red[3]) * (1.0f/512.0f);
  float d0 = v0-mean, d1 = v1-mean;
  float q = d0*d0 + d1*d1;
  #pragma unroll
  for (int off=32; off; off>>=1) q += __shfl_xor(q, off);
  if ((tid&63)==0) red[4+(tid>>6)] = q;
  __syncthreads();
  float var = (red[4]+red[5]+red[6]+red[7]) * (1.0f/512.0f);
  float rstd = rsqrtf(var + 1e-5f);
  float y0 = d0*rstd*g[tid]     + bv[tid];
  float y1 = d1*rstd*g[tid+256] + bv[tid+256];
  unsigned short h,l;
  split2(y0,h,l); hi[(size_t)row*512+tid]=h;     lo[(size_t)row*512+tid]=l;
  split2(y1,h,l); hi[(size_t)row*512+tid+256]=h; lo[(size_t)row*512+tid+256]=l;
}

// ======================= LayerNorm D=29 -> bf16 (M x 32, cols 29..31 = 0) ==========
__global__ __launch_bounds__(256) void k_ln29b(const float* __restrict__ X,
    const float* __restrict__ g, const float* __restrict__ bv, unsigned short* __restrict__ Y)
{
  int r = blockIdx.x*256 + threadIdx.x;    // rows = 131072
  const float* x = X + (size_t)r*29;
  float a[29]; float s = 0.f;
  #pragma unroll
  for (int k=0;k<29;k++){ a[k]=x[k]; s+=a[k]; }
  float mean = s*(1.0f/29.0f);
  float q = 0.f;
  #pragma unroll
  for (int k=0;k<29;k++){ float d=a[k]-mean; q+=d*d; }
  float rstd = rsqrtf(q*(1.0f/29.0f) + 1e-5f);
  unsigned short yb[32];
  #pragma unroll
  for (int k=0;k<29;k++) yb[k] = f2bf((a[k]-mean)*rstd*g[k] + bv[k]);
  yb[29]=0; yb[30]=0; yb[31]=0;
  uint4* yo = (uint4*)(Y + (size_t)r*32);
  const uint4* yi = (const uint4*)yb;
  yo[0]=yi[0]; yo[1]=yi[1]; yo[2]=yi[2]; yo[3]=yi[3];
}

// ======================= weight split+transpose: W(KxN) -> Wt hi/lo (NxK) ==========
__global__ __launch_bounds__(256) void k_split_w(const float* __restrict__ W,
    unsigned short* __restrict__ hi, int K, int N)
{
  __shared__ float t[64][65];
  unsigned short* lo = hi + (size_t)N*K;
  int k0 = blockIdx.x*64, n0 = blockIdx.y*64;
  int tid = threadIdx.x;
  #pragma unroll
  for (int i=0;i<4;i++){
    int s = tid + 256*i;
    int r = s >> 4, c4 = (s & 15)*4;
    float4 v = *(const float4*)&W[(size_t)(k0+r)*N + n0 + c4];
    t[r][c4+0]=v.x; t[r][c4+1]=v.y; t[r][c4+2]=v.z; t[r][c4+3]=v.w;
  }
  __syncthreads();
  #pragma unroll
  for (int i=0;i<4;i++){
    int s = tid + 256*i;
    int n = s >> 4, kc = (s & 15)*4;
    size_t o = (size_t)(n0+n)*K + k0 + kc;
    #pragma unroll
    for (int j=0;j<4;j++){
      unsigned short h,l; split2(t[kc+j][n], h, l);
      hi[o+j]=h; lo[o+j]=l;
    }
  }
}

// ======================= generic small transpose: src(KxN fp32) -> dst(Nd x Kd bf16, 0-pad)
__global__ __launch_bounds__(256) void k_prep_t(const float* __restrict__ src,
    unsigned short* __restrict__ dst, int K, int N, int Kd, int Nd)
{
  for (int idx = blockIdx.x*256 + threadIdx.x; idx < Nd*Kd; idx += gridDim.x*256){
    int n = idx / Kd, k = idx - n*Kd;
    float v = (k<K && n<N) ? src[(size_t)k*N + n] : 0.f;
    dst[idx] = f2bf(v);
  }
}

// ======================= W1 reorder+transpose: (29x232) -> (256x32 bf16), b1 -> b1r(256)
// dst row n: n<128 -> a-col n (valid n<116); n>=128 -> g-col 116+(n-128)
__global__ __launch_bounds__(256) void k_prep_w1(const float* __restrict__ W1,
    const float* __restrict__ b1, unsigned short* __restrict__ dst, float* __restrict__ b1r)
{
  for (int idx = blockIdx.x*256 + threadIdx.x; idx < 256*32; idx += gridDim.x*256){
    int n = idx >> 5, k = idx & 31;
    int f = n & 127, isg = n >> 7;
    float v = 0.f;
    if (f < 116 && k < 29) v = W1[(size_t)k*232 + isg*116 + f];
    dst[idx] = f2bf(v);
  }
  int n = blockIdx.x*256 + threadIdx.x;
  if (n < 256){
    int f = n & 127, isg = n >> 7;
    b1r[n] = (f < 116) ? b1[isg*116 + f] : 0.f;
  }
}

// ======================= split-bf16 MFMA GEMM (latent path, unchanged) =============
__global__ __launch_bounds__(256) void k_mfma(
    const unsigned short* __restrict__ Ahi, const unsigned short* __restrict__ Bhi,
    const float* __restrict__ bias, float* __restrict__ C,
    int M, int N, int K, int Ksplit, int accum)
{
  __shared__ unsigned short sm[4*128*32];
  int tid = threadIdx.x, lane = tid & 63, w = tid >> 6;
  int bm = blockIdx.x*128, bn = blockIdx.y*128;
  int Ks = K / Ksplit;
  int kbeg = blockIdx.z * Ks;
  const unsigned short* tsrc;
  if      (w==0) tsrc = Ahi + (size_t)bm*K;
  else if (w==1) tsrc = Ahi + (size_t)M*K + (size_t)bm*K;
  else if (w==2) tsrc = Bhi + (size_t)bn*K;
  else           tsrc = Bhi + (size_t)N*K + (size_t)bn*K;
  unsigned short* mylds = sm + w*4096;
  f32x4 acc[4][4];
  #pragma unroll
  for(int i=0;i<4;i++)
    #pragma unroll
    for(int j=0;j<4;j++) acc[i][j] = (f32x4){0.f,0.f,0.f,0.f};
  int wm = (w>>1)*64, wn = (w&1)*64;
  int frow = lane & 15, fq = lane >> 4;
  for (int k0 = kbeg; k0 < kbeg + Ks; k0 += 32){
    #pragma unroll
    for (int j=0;j<8;j++){
      int idx = j*64 + lane;
      int row = idx >> 2, qp = idx & 3;
      int q = (qp - row) & 3;
      gload16(tsrc + (size_t)row*K + k0 + q*8, mylds + j*512);
    }
    __syncthreads();
    bf16x8 ah[4], al[4];
    #pragma unroll
    for (int mt=0;mt<4;mt++){
      int row = wm + mt*16 + frow;
      int off = row*32 + ((fq + row)&3)*8;
      ah[mt] = *(const bf16x8*)(sm + off);
      al[mt] = *(const bf16x8*)(sm + 4096 + off);
    }
    #pragma unroll
    for (int nt=0;nt<4;nt++){
      int rowb = wn + nt*16 + frow;
      int offb = rowb*32 + ((fq + rowb)&3)*8;
      bf16x8 bh = *(const bf16x8*)(sm + 2*4096 + offb);
      bf16x8 bl = *(const bf16x8*)(sm + 3*4096 + offb);
      #pragma unroll
      for (int mt=0;mt<4;mt++){
        acc[mt][nt] = __builtin_amdgcn_mfma_f32_16x16x32_bf16(ah[mt], bh, acc[mt][nt], 0,0,0);
        acc[mt][nt] = __builtin_amdgcn_mfma_f32_16x16x32_bf16(ah[mt], bl, acc[mt][nt], 0,0,0);
        acc[mt][nt] = __builtin_amdgcn_mfma_f32_16x16x32_bf16(al[mt], bh, acc[mt][nt], 0,0,0);
      }
    }
    __syncthreads();
  }
  #pragma unroll
  for (int mt=0;mt<4;mt++){
    #pragma unroll
    for (int nt=0;nt<4;nt++){
      int col = bn + wn + nt*16 + frow;
      float bv = (bias && blockIdx.z==0) ? bias[col] : 0.f;
      #pragma unroll
      for (int r=0;r<4;r++){
        int row = bm + wm + mt*16 + fq*4 + r;
        float v = acc[mt][nt][r] + bv;
        if (accum) atomicAdd(&C[(size_t)row*N + col], v);
        else       C[(size_t)row*N + col] = v;
      }
    }
  }
}

// ======================= GEGLU -> split bf16 (latent FF) =======================
__global__ __launch_bounds__(256) void k_geglus(const float* __restrict__ ff1,
    unsigned short* __restrict__ hi, unsigned short* __restrict__ lo)
{
  int idx = blockIdx.x*256 + threadIdx.x;
  int m = idx >> 11, f = idx & 2047;
  float a = ff1[(size_t)m*4096 + f];
  float g = ff1[(size_t)m*4096 + 2048 + f];
  unsigned short h,l; split2(a * gelu_exact(g), h, l);
  hi[idx]=h; lo[idx]=l;
}

// ======================= KV prep: kv fp32 -> Kb bf16 (bh*256+j, 64) and Vt (bh*64+d, 256)
__global__ __launch_bounds__(256) void k_kvprep(const float* __restrict__ kv, int ld,
    int koff, int voff, int heads, int BH,
    unsigned short* __restrict__ Kb, unsigned short* __restrict__ Vthi,
    unsigned short* __restrict__ Vtlo)
{
  int total = BH << 14;
  for (int idx = blockIdx.x*256 + threadIdx.x; idx < total; idx += gridDim.x*256){
    int d = idx & 63, j = (idx>>6) & 255, bh = idx >> 14;
    int b = bh / heads, h = bh - b*heads;
    Kb[idx] = f2bf(kv[((size_t)(b*256 + j))*ld + koff + h*64 + d]);
  }
  for (int idx = blockIdx.x*256 + threadIdx.x; idx < total; idx += gridDim.x*256){
    int j = idx & 255, d = (idx>>8) & 63, bh = idx >> 14;
    int b = bh / heads, h = bh - b*heads;
    float v = kv[((size_t)(b*256 + j))*ld + voff + h*64 + d];
    if (Vtlo){ unsigned short hh,ll; split2(v,hh,ll); Vthi[idx]=hh; Vtlo[idx]=ll; }
    else Vthi[idx] = f2bf(v);
  }
}

// ======================= MFMA attention: 16 queries/wave, 256 keys, dh=64 ==========
// Kb: (bh*256+key, 64) bf16.  Vt: (bh*64+dim, 256) bf16 [+lo if SPLITV].
// In-register softmax (C-layout rows = quad*4+reg), P->A-layout via per-wave LDS.
template<int QF32, int SPLITV, int OSPLIT>
__global__ __launch_bounds__(256) void k_attn_mf(
    const void* __restrict__ Qv, const unsigned short* __restrict__ Kb,
    const unsigned short* __restrict__ Vthi, const unsigned short* __restrict__ Vtlo,
    unsigned short* __restrict__ O0, unsigned short* __restrict__ O1,
    int q_rs, int o_rs, int heads, int nper, float scale)
{
  __shared__ unsigned short Pw[4*640];   // per-wave 16x40 (stride 40 => 16B-aligned rows)
  int tid = threadIdx.x, lane = tid & 63, w = tid >> 6;
  int l15 = lane & 15, g = lane >> 4;
  int bpb = nper >> 6;
  int bh = blockIdx.x / bpb;
  int q0 = (blockIdx.x - bh*bpb)*64 + w*16;
  int b = bh / heads, h = bh - b*heads;
  // Q A-frags (2 k-tiles of 32)
  bf16x8 aq[2];
  int qrow = b*nper + q0 + l15;
  if (QF32){
    const float* qp = (const float*)Qv + (size_t)qrow*q_rs + h*64 + g*8;
    #pragma unroll
    for (int kt=0;kt<2;kt++){
      bf16x8 v;
      #pragma unroll
      for (int j=0;j<8;j++) v[j] = (__bf16)qp[kt*32 + j];
      aq[kt]=v;
    }
  } else {
    const unsigned short* qp = (const unsigned short*)Qv + (size_t)qrow*q_rs + h*64 + g*8;
    aq[0] = *(const bf16x8*)(qp);
    aq[1] = *(const bf16x8*)(qp + 32);
  }
  // scores: 16 n-tiles x 2 k-tiles
  const unsigned short* kbb = Kb + ((size_t)bh*256 + l15)*64 + g*8;
  f32x4 sc[16];
  #pragma unroll
  for (int nt=0;nt<16;nt++) sc[nt] = (f32x4){0.f,0.f,0.f,0.f};
  #pragma unroll
  for (int nt=0;nt<16;nt++){
    bf16x8 b0 = *(const bf16x8*)(kbb + (size_t)nt*1024);
    bf16x8 b1 = *(const bf16x8*)(kbb + (size_t)nt*1024 + 32);
    sc[nt] = __builtin_amdgcn_mfma_f32_16x16x32_bf16(aq[0], b0, sc[nt], 0,0,0);
    sc[nt] = __builtin_amdgcn_mfma_f32_16x16x32_bf16(aq[1], b1, sc[nt], 0,0,0);
  }
  // softmax in-register: row = g*4 + r, reduce across the 16-lane group
  float mx[4] = {-1e30f,-1e30f,-1e30f,-1e30f};
  #pragma unroll
  for (int nt=0;nt<16;nt++)
    #pragma unroll
    for (int r=0;r<4;r++){ float v = sc[nt][r]*scale; sc[nt][r]=v; mx[r]=fmaxf(mx[r],v); }
  #pragma unroll
  for (int r=0;r<4;r++){
    #pragma unroll
    for (int m=1;m<16;m<<=1) mx[r] = fmaxf(mx[r], __shfl_xor(mx[r], m));
  }
  float sum[4] = {0.f,0.f,0.f,0.f};
  #pragma unroll
  for (int nt=0;nt<16;nt++)
    #pragma unroll
    for (int r=0;r<4;r++){ float e = __expf(sc[nt][r]-mx[r]); sc[nt][r]=e; sum[r]+=e; }
  #pragma unroll
  for (int r=0;r<4;r++){
    #pragma unroll
    for (int m=1;m<16;m<<=1) sum[r] += __shfl_xor(sum[r], m);
  }
  // PV: 8 key-chunks of 32; P C-layout -> LDS -> A-layout
  f32x4 o[4];
  #pragma unroll
  for (int nd=0;nd<4;nd++) o[nd] = (f32x4){0.f,0.f,0.f,0.f};
  unsigned short* pw = Pw + w*640;
  const unsigned short* vb  = Vthi + ((size_t)bh*64 + l15)*256 + g*8;
  const unsigned short* vbl = SPLITV ? (Vtlo + ((size_t)bh*64 + l15)*256 + g*8) : (const unsigned short*)0;
  #pragma unroll
  for (int kt=0;kt<8;kt++){
    __builtin_amdgcn_wave_barrier();
    #pragma unroll
    for (int t2=0;t2<2;t2++){
      int nt = kt*2 + t2;
      #pragma unroll
      for (int r=0;r<4;r++)
        pw[(g*4+r)*40 + t2*16 + l15] = f2bf(sc[nt][r]);
    }
    __builtin_amdgcn_wave_barrier();
    bf16x8 ap = *(const bf16x8*)(pw + l15*40 + g*8);
    #pragma unroll
    for (int nd=0;nd<4;nd++){
      bf16x8 bv = *(const bf16x8*)(vb + (size_t)nd*4096 + kt*32);
      o[nd] = __builtin_amdgcn_mfma_f32_16x16x32_bf16(ap, bv, o[nd], 0,0,0);
      if (SPLITV){
        bf16x8 bl = *(const bf16x8*)(vbl + (size_t)nd*4096 + kt*32);
        o[nd] = __builtin_amdgcn_mfma_f32_16x16x32_bf16(ap, bl, o[nd], 0,0,0);
      }
    }
  }
  // epilogue
  float inv[4];
  #pragma unroll
  for (int r=0;r<4;r++) inv[r] = 1.0f/sum[r];
  int orow0 = b*nper + q0;
  #pragma unroll
  for (int nd=0;nd<4;nd++){
    #pragma unroll
    for (int r=0;r<4;r++){
      float v = o[nd][r]*inv[r];
      size_t off = (size_t)(orow0 + g*4 + r)*o_rs + h*64 + nd*16 + l15;
      if (OSPLIT){ unsigned short hh,ll; split2(v,hh,ll); O0[off]=hh; O1[off]=ll; }
      else O0[off] = f2bf(v);
    }
  }
}

// ======================= q_c = qn_b(Mx32) @ WqT(64x32)^T -> bf16 (Mx64) ============
__global__ __launch_bounds__(256) void k_qproj(const unsigned short* __restrict__ A,
    const unsigned short* __restrict__ Wt, unsigned short* __restrict__ Out)
{
  int tid = threadIdx.x, lane = tid & 63, w = tid >> 6;
  int l15 = lane & 15, g = lane >> 4;
  int row0 = blockIdx.x*128 + w*32;
  bf16x8 a0 = *(const bf16x8*)(A + (size_t)(row0 + l15)*32 + g*8);
  bf16x8 a1 = *(const bf16x8*)(A + (size_t)(row0 + 16 + l15)*32 + g*8);
  f32x4 acc[2][4];
  #pragma unroll
  for (int mt=0;mt<2;mt++)
    #pragma unroll
    for (int nt=0;nt<4;nt++) acc[mt][nt] = (f32x4){0.f,0.f,0.f,0.f};
  #pragma unroll
  for (int nt=0;nt<4;nt++){
    bf16x8 bw = *(const bf16x8*)(Wt + (size_t)(nt*16 + l15)*32 + g*8);
    acc[0][nt] = __builtin_amdgcn_mfma_f32_16x16x32_bf16(a0, bw, acc[0][nt], 0,0,0);
    acc[1][nt] = __builtin_amdgcn_mfma_f32_16x16x32_bf16(a1, bw, acc[1][nt], 0,0,0);
  }
  #pragma unroll
  for (int mt=0;mt<2;mt++)
    #pragma unroll
    for (int nt=0;nt<4;nt++)
      #pragma unroll
      for (int r=0;r<4;r++)
        Out[(size_t)(row0 + mt*16 + g*4 + r)*64 + nt*16 + l15] = f2bf(acc[mt][nt][r]);
}

// ======================= data(Mx29) += A(MxK bf16) @ Wt(32xK)^T + bias =============
__global__ __launch_bounds__(256) void k_nsmall(const unsigned short* __restrict__ A,
    const unsigned short* __restrict__ Wt, const float* __restrict__ bias,
    float* __restrict__ C, int K)
{
  int tid = threadIdx.x, lane = tid & 63, w = tid >> 6;
  int l15 = lane & 15, g = lane >> 4;
  int row0 = blockIdx.x*128 + w*32;
  f32x4 acc[2][2];
  #pragma unroll
  for (int mt=0;mt<2;mt++)
    #pragma unroll
    for (int nt=0;nt<2;nt++) acc[mt][nt] = (f32x4){0.f,0.f,0.f,0.f};
  for (int kt=0; kt<K; kt+=32){
    bf16x8 a0 = *(const bf16x8*)(A + (size_t)(row0 + l15)*K + kt + g*8);
    bf16x8 a1 = *(const bf16x8*)(A + (size_t)(row0 + 16 + l15)*K + kt + g*8);
    #pragma unroll
    for (int nt=0;nt<2;nt++){
      bf16x8 bw = *(const bf16x8*)(Wt + (size_t)(nt*16 + l15)*K + kt + g*8);
      acc[0][nt] = __builtin_amdgcn_mfma_f32_16x16x32_bf16(a0, bw, acc[0][nt], 0,0,0);
      acc[1][nt] = __builtin_amdgcn_mfma_f32_16x16x32_bf16(a1, bw, acc[1][nt], 0,0,0);
    }
  }
  #pragma unroll
  for (int mt=0;mt<2;mt++)
    #pragma unroll
    for (int nt=0;nt<2;nt++){
      int col = nt*16 + l15;
      if (col < 29){
        #pragma unroll
        for (int r=0;r<4;r++){
          size_t off = (size_t)(row0 + mt*16 + g*4 + r)*29 + col;
          C[off] += acc[mt][nt][r] + bias[col];
        }
      }
    }
}

// ======================= gg = GEGLU(qn_b @ W1rT + b1r) -> bf16 (Mx128) =============
// W1rT reordered: n-tiles 0..7 = a-cols, 8..15 = g-cols (same within-tile lane)
__global__ __launch_bounds__(256) void k_ff1(const unsigned short* __restrict__ A,
    const unsigned short* __restrict__ Wt, const float* __restrict__ b1r,
    unsigned short* __restrict__ G)
{
  int tid = threadIdx.x, lane = tid & 63, w = tid >> 6;
  int l15 = lane & 15, g = lane >> 4;
  int row0 = blockIdx.x*128 + w*32;
  bf16x8 a0 = *(const bf16x8*)(A + (size_t)(row0 + l15)*32 + g*8);
  bf16x8 a1 = *(const bf16x8*)(A + (size_t)(row0 + 16 + l15)*32 + g*8);
  f32x4 acc[2][16];
  #pragma unroll
  for (int mt=0;mt<2;mt++)
    #pragma unroll
    for (int nt=0;nt<16;nt++) acc[mt][nt] = (f32x4){0.f,0.f,0.f,0.f};
  #pragma unroll
  for (int nt=0;nt<16;nt++){
    bf16x8 bw = *(const bf16x8*)(Wt + (size_t)(nt*16 + l15)*32 + g*8);
    acc[0][nt] = __builtin_amdgcn_mfma_f32_16x16x32_bf16(a0, bw, acc[0][nt], 0,0,0);
    acc[1][nt] = __builtin_amdgcn_mfma_f32_16x16x32_bf16(a1, bw, acc[1][nt], 0,0,0);
  }
  #pragma unroll
  for (int mt=0;mt<2;mt++){
    #pragma unroll
    for (int t=0;t<8;t++){
      float ba = b1r[t*16 + l15];
      float bg = b1r[128 + t*16 + l15];
      #pragma unroll
      for (int r=0;r<4;r++){
        float av = acc[mt][t][r]   + ba;
        float gv = acc[mt][t+8][r] + bg;
        G[(size_t)(row0 + mt*16 + g*4 + r)*128 + t*16 + l15] = f2bf(av * gelu_exact(gv));
      }
    }
  }
}

// ======================= output =======================
__global__ __launch_bounds__(256) void k_out(const float* __restrict__ data, float* __restrict__ out)
{
  int idx = blockIdx.x*256 + threadIdx.x;
  int p = idx/3, c = idx - p*3;
  out[idx] = data[(size_t)p*29 + c];
}

// =====================================================================
extern "C" void kernel_launch(void* const* d_in, const int* in_sizes, int n_in,
                              void* d_out, int out_size, void* d_ws, size_t ws_size,
                              hipStream_t stream) {
  const float* x        = (const float*)d_in[0];
  const float* latents  = (const float*)d_in[1];
  const float* W_l2l    = (const float*)d_in[2];
  const float* b_l2l    = (const float*)d_in[3];
  const float* ca_ln_q_g= (const float*)d_in[4];
  const float* ca_ln_q_b= (const float*)d_in[5];
  const float* ca_ln_c_g= (const float*)d_in[6];
  const float* ca_ln_c_b= (const float*)d_in[7];
  const float* ca_Wq    = (const float*)d_in[8];
  const float* ca_Wkv   = (const float*)d_in[9];
  const float* ca_Wo    = (const float*)d_in[10];
  const float* ca_bo    = (const float*)d_in[11];
  const float* cf_ln_g  = (const float*)d_in[12];
  const float* cf_ln_b  = (const float*)d_in[13];
  const float* cf_W1    = (const float*)d_in[14];
  const float* cf_b1    = (const float*)d_in[15];
  const float* cf_W2    = (const float*)d_in[16];
  const float* cf_b2    = (const float*)d_in[17];
  const float* la_ln_g  = (const float*)d_in[18];
  const float* la_ln_b  = (const float*)d_in[19];
  const float* la_Wq    = (const float*)d_in[20];
  const float* la_Wkv   = (const float*)d_in[21];
  const float* la_Wo    = (const float*)d_in[22];
  const float* la_bo    = (const float*)d_in[23];
  const float* lf_ln_g  = (const float*)d_in[24];
  const float* lf_ln_b  = (const float*)d_in[25];
  const float* lf_W1    = (const float*)d_in[26];
  const float* lf_b1    = (const float*)d_in[27];
  const float* lf_W2    = (const float*)d_in[28];
  const float* lf_b2    = (const float*)d_in[29];

  float* ws = (float*)d_ws;
  // ---- layout (floats), total ~25.24M f = 101 MB ----
  float* data = ws;                                   // 3,801,088
  float* lat  = ws + 3801088;                         // 1,048,576
  unsigned short* latn_hi = (unsigned short*)(ws + 4849664); // 2048*512 hi|lo
  unsigned short* latn_lo = latn_hi + 1048576;
  float* I    = ws + 5898240;                         // 14,680,064 arena
  float* kv_c = ws + 20578304;                        // 262,144
  unsigned short* Kb_c = (unsigned short*)(ws + 20840448);   // 131,072 ush
  unsigned short* Vt_c = Kb_c + 131072;                       // 131,072 ush
  unsigned short* wsp  = (unsigned short*)(ws + 20971520);
  unsigned short* wqt  = wsp;             // 512x512  hi|lo
  unsigned short* wkvt = wsp + 524288;    // 1024x512 hi|lo
  unsigned short* wot  = wsp + 1572864;   // 512x512  hi|lo
  unsigned short* w1t  = wsp + 2097152;   // 4096x512 hi|lo
  unsigned short* w2t  = wsp + 6291456;   // 512x2048 hi|lo
  unsigned short* cakvt= wsp + 8388608;   // 128x512  hi|lo
  unsigned short* WqT  = wsp + 8519680;   // 64x32
  unsigned short* WoT  = wsp + 8521728;   // 32x64
  unsigned short* W2T  = wsp + 8523776;   // 32x128
  unsigned short* W1rT = wsp + 8527872;   // 256x32
  float* b1r = (float*)(wsp + 8536064);   // 256 f
  // arena I aliases (temporally disjoint):
  float* q_l  = I;                                      // 2048x512 f
  float* kv_l = I + 1048576;                            // 2048x1024 f
  unsigned short* Kb_l   = (unsigned short*)(I + 3145728);  // 64*256*64
  unsigned short* Vthi_l = Kb_l + 1048576;
  unsigned short* Vtlo_l = Vthi_l + 1048576;
  unsigned short* ao_hi  = (unsigned short*)(I + 4718592);  // 2048x512 hi|lo
  unsigned short* ao_lo  = ao_hi + 1048576;
  float* ff1 = I;                                       // 2048x4096 f
  unsigned short* gg_hi = (unsigned short*)(I + 8388608);   // 2048x2048 hi|lo
  unsigned short* gg_lo = gg_hi + 4194304;
  unsigned short* qn_b = (unsigned short*)I;                // 131072x32
  unsigned short* q_c  = (unsigned short*)(I + 2097152);    // 131072x64 (= ao_b)
  unsigned short* gg_c = (unsigned short*)(I + 6291456);    // 131072x128

  k_encode<<<64, 256, 0, stream>>>(data);
  k_l2l   <<<512, 256, 0, stream>>>(x, W_l2l, b_l2l, latents, lat);

  for (int i=0;i<4;i++){
    // ---- weight preps ----
    k_split_w<<<dim3(8,8),  256,0,stream>>>(la_Wq +(size_t)i*262144,  wqt,  512, 512);
    k_split_w<<<dim3(8,16), 256,0,stream>>>(la_Wkv+(size_t)i*524288,  wkvt, 512, 1024);
    k_split_w<<<dim3(8,8),  256,0,stream>>>(la_Wo +(size_t)i*262144,  wot,  512, 512);
    k_split_w<<<dim3(8,64), 256,0,stream>>>(lf_W1 +(size_t)i*2097152, w1t,  512, 4096);
    k_split_w<<<dim3(32,8), 256,0,stream>>>(lf_W2 +(size_t)i*1048576, w2t,  2048, 512);
    k_split_w<<<dim3(8,2),  256,0,stream>>>(ca_Wkv+(size_t)i*65536,   cakvt,512, 128);
    k_prep_t <<<4,256,0,stream>>>(ca_Wq+(size_t)i*1856, WqT, 29, 64, 32, 64);
    k_prep_t <<<4,256,0,stream>>>(ca_Wo+(size_t)i*1856, WoT, 64, 29, 64, 32);
    k_prep_t <<<8,256,0,stream>>>(cf_W2+(size_t)i*3364, W2T, 116, 29, 128, 32);
    k_prep_w1<<<32,256,0,stream>>>(cf_W1+(size_t)i*6728, cf_b1+i*232, W1rT, b1r);
    // ---- latent self-attention ----
    k_ln512s<<<2048,256,0,stream>>>(lat, la_ln_g+i*512, la_ln_b+i*512, latn_hi, latn_lo);
    k_mfma<<<dim3(16,4,1),256,0,stream>>>(latn_hi, wqt,  nullptr, q_l,  2048, 512, 512, 1, 0);
    k_mfma<<<dim3(16,8,1),256,0,stream>>>(latn_hi, wkvt, nullptr, kv_l, 2048,1024, 512, 1, 0);
    k_kvprep<<<1024,256,0,stream>>>(kv_l, 1024, 0, 512, 8, 64, Kb_l, Vthi_l, Vtlo_l);
    k_attn_mf<1,1,1><<<256,256,0,stream>>>(q_l, Kb_l, Vthi_l, Vtlo_l, ao_hi, ao_lo,
                                           512, 512, 8, 256, 0.125f);
    k_mfma<<<dim3(16,4,2),256,0,stream>>>(ao_hi, wot, la_bo+i*512, lat, 2048, 512, 512, 2, 1);
    // ---- latent GEGLU FF ----
    k_ln512s<<<2048,256,0,stream>>>(lat, lf_ln_g+i*512, lf_ln_b+i*512, latn_hi, latn_lo);
    k_mfma<<<dim3(16,32,1),256,0,stream>>>(latn_hi, w1t, lf_b1+i*4096, ff1, 2048, 4096, 512, 1, 0);
    k_geglus<<<16384,256,0,stream>>>(ff1, gg_hi, gg_lo);
    k_mfma<<<dim3(16,4,4),256,0,stream>>>(gg_hi, w2t, lf_b2+i*512, lat, 2048, 512, 2048, 4, 1);
    // ---- cross-attention ----
    k_ln512s<<<2048,256,0,stream>>>(lat, ca_ln_c_g+i*512, ca_ln_c_b+i*512, latn_hi, latn_lo);
    k_mfma<<<dim3(16,1,1),256,0,stream>>>(latn_hi, cakvt, nullptr, kv_c, 2048, 128, 512, 1, 0);
    k_kvprep<<<512,256,0,stream>>>(kv_c, 128, 0, 64, 1, 8, Kb_c, Vt_c, nullptr);
    k_ln29b<<<512,256,0,stream>>>(data, ca_ln_q_g+i*29, ca_ln_q_b+i*29, qn_b);
    k_qproj<<<1024,256,0,stream>>>(qn_b, WqT, q_c);
    k_attn_mf<0,0,0><<<2048,256,0,stream>>>(q_c, Kb_c, Vt_c, nullptr, q_c, nullptr,
                                            64, 64, 1, 16384, 0.125f);
    k_nsmall<<<1024,256,0,stream>>>(q_c, WoT, ca_bo+i*29, data, 64);
    // ---- cross GEGLU FF ----
    k_ln29b<<<512,256,0,stream>>>(data, cf_ln_g+i*29, cf_ln_b+i*29, qn_b);
    k_ff1<<<1024,256,0,stream>>>(qn_b, W1rT, b1r, gg_c);
    k_nsmall<<<1024,256,0,stream>>>(gg_c, W2T, cf_b2+i*29, data, 128);
  }

  k_out<<<1536,256,0,stream>>>(data, (float*)d_out);
}